// Round 9
// baseline (47.985 us; speedup 1.0000x reference)
//
#include <hip/hip_runtime.h>

// input x: (B=256,T=600,J=25,C=3) f32; x[b,tt,n*5+p,c] = in[(b*600+tt)*75 + n*15 + p*3 + c]
// output: (B,5,1800,4,4) f32, windows concatenated along tout.
// Window-group g in {0,1,2}: tout = g*600 + tt. Boundary slots (center-only cov):
//   g0: tt in {0,599}; g1: tt%300 in {0,299}; g2: tt%200 in {0,199}.
//
// R9: block = (b, n, g, 300-tt half) -> each block writes ONE contiguous 19.2KB
// output run (vs R7's 15 interleaved 6.4KB streams). Stage = n's 15-float column
// (301 rows w/ halo, 18KB LDS); compute slot-per-thread; store cooperatively
// lane-contiguous from bank-padded obuf. XCD swizzle: b%8 == blk%8 so blocks
// sharing b's input lines hit the same L2.

#define T_ 600

__global__ __launch_bounds__(256) void gauss_agg_kernel(const float* __restrict__ x,
                                                        float* __restrict__ out) {
    __shared__ float raw[301 * 15];    // 18.1 KB: staged column (300 tt + halo)
    __shared__ float4 obuf[256 * 5];   // 20 KB; 80B/slot stride avoids bank aliasing

    // swizzle: blk -> (b,n,g,half) with b%8 == blk%8
    int blk = blockIdx.x;
    int oct = blk & 7;
    int inner = blk >> 3;              // 0..959
    int bh = inner / 30;               // b>>3
    int r  = inner - bh * 30;          // n*6 + g*2 + half
    int n = r / 6;
    int r2 = r - n * 6;
    int g = r2 >> 1;
    int half = r2 & 1;
    int b = oct + 8 * bh;
    int tt0 = half * 300;

    int start = tt0 - 1; if (start < 0) start = 0;
    int end   = tt0 + 301; if (end > T_) end = T_;
    int nrows = end - start;           // 301
    int ofs   = tt0 - start;           // 0 (half 0) or 1 (half 1)

    // ---- stage n's 15-float column (60B chunks, stride 300B) ----
    const float* src = x + ((size_t)b * T_ + start) * 75 + n * 15;
    int tot = nrows * 15;
    for (int e = (int)threadIdx.x; e < tot; e += 256) {
        int row = e / 15;
        int c   = e - row * 15;
        raw[e] = src[row * 75 + c];
    }
    __syncthreads();

    const float w5[5] = {4.f, 2.f, 3.f, 2.f, 4.f};
    float4* outf4 = reinterpret_cast<float4*>(out);
    size_t obase = ((size_t)(b * 5 + n) * 1800 + g * 600 + tt0) * 4;

    // ---- 2 batches: 256 + 44 slots ----
    for (int m = 0; m < 2; ++m) {
        int tl = m * 256 + (int)threadIdx.x;   // slot within the 300-run
        if (tl < 300) {
            int tt = tt0 + tl;
            int li = tl + ofs;

            bool boundary;
            if (g == 0)      boundary = (tt == 0) || (tt == 599);
            else if (g == 1) { int q = tt % 300; boundary = (q == 0) || (q == 299); }
            else             { int q = tt % 200; boundary = (q == 0) || (q == 199); }

            const float* rc = &raw[li * 15];

            float s0=0.f,s1=0.f,s2=0.f, m0=0.f,m1=0.f,m2=0.f;
            float A00=0.f,A01=0.f,A02=0.f,A11=0.f,A12=0.f,A22=0.f;
            #pragma unroll
            for (int p = 0; p < 5; ++p) {
                float a = rc[p*3+0], c = rc[p*3+1], d = rc[p*3+2];
                s0 += a; s1 += c; s2 += d;
                m0 += w5[p]*a; m1 += w5[p]*c; m2 += w5[p]*d;
                A00 += a*a; A01 += a*c; A02 += a*d;
                A11 += c*c; A12 += c*d; A22 += d*d;
            }
            float mu0 = m0*(1.f/15.f), mu1 = m1*(1.f/15.f), mu2 = m2*(1.f/15.f);

            float inv = 0.2f;
            if (!boundary) {   // interior: li-1 and li+1 staged by construction
                #pragma unroll
                for (int dstep = 0; dstep < 2; ++dstep) {
                    const float* rn = rc + (dstep ? 15 : -15);
                    #pragma unroll
                    for (int p = 0; p < 5; ++p) {
                        float a = rn[p*3+0], c = rn[p*3+1], d = rn[p*3+2];
                        s0 += a; s1 += c; s2 += d;
                        A00 += a*a; A01 += a*c; A02 += a*d;
                        A11 += c*c; A12 += c*d; A22 += d*d;
                    }
                }
                inv = 1.f/15.f;
            }

            float mb0 = s0*inv, mb1 = s1*inv, mb2 = s2*inv;
            float e00 = A00*inv - 2.f*mu0*mb0 + 2.f*mu0*mu0;
            float e01 = A01*inv - mu0*mb1 - mb0*mu1 + 2.f*mu0*mu1;
            float e02 = A02*inv - mu0*mb2 - mb0*mu2 + 2.f*mu0*mu2;
            float e11 = A11*inv - 2.f*mu1*mb1 + 2.f*mu1*mu1;
            float e12 = A12*inv - mu1*mb2 - mb1*mu2 + 2.f*mu1*mu2;
            float e22 = A22*inv - 2.f*mu2*mb2 + 2.f*mu2*mu2;

            int base = (int)threadIdx.x * 5;
            obuf[base + 0] = make_float4(e00, e01, e02, mu0);
            obuf[base + 1] = make_float4(e01, e11, e12, mu1);
            obuf[base + 2] = make_float4(e02, e12, e22, mu2);
            obuf[base + 3] = make_float4(mu0, mu1, mu2, 1.f);
        }
        __syncthreads();

        // ---- cooperative store: ONE contiguous run ----
        int nslots = 300 - m * 256; if (nslots > 256) nslots = 256;
        int npieces = nslots * 4;
        #pragma unroll
        for (int k = 0; k < 4; ++k) {
            int f = k * 256 + (int)threadIdx.x;
            if (f < npieces) {
                int sl = f >> 2, pc = f & 3;
                outf4[obase + (size_t)(m * 256 + sl) * 4 + pc] = obuf[sl * 5 + pc];
            }
        }
        __syncthreads();
    }
}

extern "C" void kernel_launch(void* const* d_in, const int* in_sizes, int n_in,
                              void* d_out, int out_size, void* d_ws, size_t ws_size,
                              hipStream_t stream) {
    const float* x = (const float*)d_in[0];
    float* out = (float*)d_out;
    gauss_agg_kernel<<<256 * 30, 256, 0, stream>>>(x, out);   // 7680 blocks
}

// Round 10
// 42.408 us; speedup vs baseline: 1.1315x; 1.1315x over previous
//
#include <hip/hip_runtime.h>

// input x: (B=256,T=600,J=25,C=3) f32; x[b,tt,n*5+p,c] = in[(b*600+tt)*75 + n*15 + p*3 + c]
// output: (B,5,1800,4,4) f32, windows concatenated along tout.
//
// R10 = R7 (proven 42.1us: coalesced LDS stage -> slot-per-thread compute ->
// bank-padded obuf -> lane-contiguous cooperative store) with one change:
// __syncthreads() replaced by {s_waitcnt lgkmcnt(0); s_barrier}. __syncthreads'
// compiler-emitted vmcnt(0) drained ALL outstanding global stores at every one
// of the 12 barriers/block; the only real cross-thread deps here are LDS
// (raw/obuf), so lgkmcnt(0) suffices and stores stay in flight across batches.

#define T_ 600
#define CH_ 100
#define NCH_ 6

// LDS-only barrier: order LDS ops (lgkmcnt) but let global stores float.
#define BAR_LDS() do { asm volatile("s_waitcnt lgkmcnt(0)" ::: "memory"); \
                       __builtin_amdgcn_s_barrier(); } while (0)

__global__ __launch_bounds__(256) void gauss_agg_kernel(const float* __restrict__ x,
                                                        float* __restrict__ out) {
    __shared__ float raw[102 * 75];      // 30.6 KB staged input (chunk + halo)
    __shared__ float4 obuf[256 * 5];     // 20 KB; 80B/slot stride kills bank aliasing

    int blk = blockIdx.x;
    int ch  = blk % NCH_;
    int b   = blk / NCH_;

    int start = ch * CH_ - 1; if (start < 0) start = 0;
    int end   = ch * CH_ + CH_ + 1; if (end > T_) end = T_;
    int total = (end - start) * 75;

    // ---- phase 0: dense coalesced stage ----
    const float* src = x + ((size_t)b * T_ + start) * 75;
    for (int e = (int)threadIdx.x; e < total; e += 256) raw[e] = src[e];
    BAR_LDS();

    int ofs = (ch == 0) ? 0 : 1;     // local row of tt = (tt - ch*CH_) + ofs
    const float w5[5] = {4.f, 2.f, 3.f, 2.f, 4.f};
    float4* outf4 = reinterpret_cast<float4*>(out);

    // ---- 6 batches of 256 slots (1500 = 5n x 3w x 100tt) ----
    for (int m = 0; m < 6; ++m) {
        int s = m * 256 + (int)threadIdx.x;
        if (s < 1500) {
            int n  = s / 300;
            int q  = s - n * 300;
            int w  = q / 100;
            int tl = q - w * 100;
            int tt = ch * CH_ + tl;
            int li = tl + ofs;

            bool boundary;
            if (w == 0)      boundary = (tt == 0) || (tt == 599);
            else if (w == 1) boundary = (tt == 0) || (tt == 299) || (tt == 300) || (tt == 599);
            else             boundary = (tt == 0) || (tt == 199) || (tt == 200) ||
                                        (tt == 399) || (tt == 400) || (tt == 599);

            const float* rc = &raw[li * 75 + n * 15];

            float s0=0.f,s1=0.f,s2=0.f, m0=0.f,m1=0.f,m2=0.f;
            float A00=0.f,A01=0.f,A02=0.f,A11=0.f,A12=0.f,A22=0.f;
            #pragma unroll
            for (int p = 0; p < 5; ++p) {
                float a = rc[p*3+0], c = rc[p*3+1], d = rc[p*3+2];
                s0 += a; s1 += c; s2 += d;
                m0 += w5[p]*a; m1 += w5[p]*c; m2 += w5[p]*d;
                A00 += a*a; A01 += a*c; A02 += a*d;
                A11 += c*c; A12 += c*d; A22 += d*d;
            }
            float mu0 = m0*(1.f/15.f), mu1 = m1*(1.f/15.f), mu2 = m2*(1.f/15.f);

            float inv = 0.2f;
            if (!boundary) {
                #pragma unroll
                for (int dstep = 0; dstep < 2; ++dstep) {
                    const float* rn = rc + (dstep ? 75 : -75);
                    #pragma unroll
                    for (int p = 0; p < 5; ++p) {
                        float a = rn[p*3+0], c = rn[p*3+1], d = rn[p*3+2];
                        s0 += a; s1 += c; s2 += d;
                        A00 += a*a; A01 += a*c; A02 += a*d;
                        A11 += c*c; A12 += c*d; A22 += d*d;
                    }
                }
                inv = 1.f/15.f;
            }

            float mb0 = s0*inv, mb1 = s1*inv, mb2 = s2*inv;
            float e00 = A00*inv - 2.f*mu0*mb0 + 2.f*mu0*mu0;
            float e01 = A01*inv - mu0*mb1 - mb0*mu1 + 2.f*mu0*mu1;
            float e02 = A02*inv - mu0*mb2 - mb0*mu2 + 2.f*mu0*mu2;
            float e11 = A11*inv - 2.f*mu1*mb1 + 2.f*mu1*mu1;
            float e12 = A12*inv - mu1*mb2 - mb1*mu2 + 2.f*mu1*mu2;
            float e22 = A22*inv - 2.f*mu2*mb2 + 2.f*mu2*mu2;

            int base = (int)threadIdx.x * 5;
            obuf[base + 0] = make_float4(e00, e01, e02, mu0);
            obuf[base + 1] = make_float4(e01, e11, e12, mu1);
            obuf[base + 2] = make_float4(e02, e12, e22, mu2);
            obuf[base + 3] = make_float4(mu0, mu1, mu2, 1.f);
        }
        BAR_LDS();

        // ---- cooperative lane-contiguous store of this batch ----
        int nslots  = (1500 - m * 256 < 256) ? (1500 - m * 256) : 256;
        int npieces = nslots * 4;
        #pragma unroll
        for (int k = 0; k < 4; ++k) {
            int f = k * 256 + (int)threadIdx.x;
            if (f < npieces) {
                int sl = f >> 2, pc = f & 3;
                int s2 = m * 256 + sl;
                int n  = s2 / 300;
                int q  = s2 - n * 300;
                int w  = q / 100;
                int tl = q - w * 100;
                int tt = ch * CH_ + tl;
                size_t o = ((size_t)(b * 5 + n) * 1800 + w * 600 + tt) * 4 + pc;
                outf4[o] = obuf[sl * 5 + pc];
            }
        }
        BAR_LDS();
    }
}

extern "C" void kernel_launch(void* const* d_in, const int* in_sizes, int n_in,
                              void* d_out, int out_size, void* d_ws, size_t ws_size,
                              hipStream_t stream) {
    const float* x = (const float*)d_in[0];
    float* out = (float*)d_out;
    gauss_agg_kernel<<<256 * NCH_, 256, 0, stream>>>(x, out);
}

// Round 12
// 41.185 us; speedup vs baseline: 1.1651x; 1.0297x over previous
//
#include <hip/hip_runtime.h>

// input x: (B=256,T=600,J=25,C=3) f32; x[b,tt,n*5+p,c] = in[(b*600+tt)*75 + n*15 + p*3 + c]
// output: (B,5,1800,4,4) f32, windows concatenated along tout.
//
// R12 = R10 (42.4us: coalesced LDS stage -> slot-per-thread compute -> bank-padded
// obuf -> lane-contiguous cooperative store; lgkm-only barriers) + nontemporal
// output stores (nt bit: no L2 allocation for the 147MB streaming write stream).
// R11's compile error fixed: use a native ext_vector_type(4) float for the builtin.

#define T_ 600
#define CH_ 100
#define NCH_ 6

typedef float fx4 __attribute__((ext_vector_type(4)));

// LDS-only barrier: order LDS ops (lgkmcnt) but let global stores float.
#define BAR_LDS() do { asm volatile("s_waitcnt lgkmcnt(0)" ::: "memory"); \
                       __builtin_amdgcn_s_barrier(); } while (0)

__global__ __launch_bounds__(256) void gauss_agg_kernel(const float* __restrict__ x,
                                                        float* __restrict__ out) {
    __shared__ float raw[102 * 75];      // 30.6 KB staged input (chunk + halo)
    __shared__ float4 obuf[256 * 5];     // 20 KB; 80B/slot stride kills bank aliasing

    int blk = blockIdx.x;
    int ch  = blk % NCH_;
    int b   = blk / NCH_;

    int start = ch * CH_ - 1; if (start < 0) start = 0;
    int end   = ch * CH_ + CH_ + 1; if (end > T_) end = T_;
    int total = (end - start) * 75;

    // ---- phase 0: dense coalesced stage ----
    const float* src = x + ((size_t)b * T_ + start) * 75;
    for (int e = (int)threadIdx.x; e < total; e += 256) raw[e] = src[e];
    BAR_LDS();

    int ofs = (ch == 0) ? 0 : 1;     // local row of tt = (tt - ch*CH_) + ofs
    const float w5[5] = {4.f, 2.f, 3.f, 2.f, 4.f};
    fx4* outf4 = reinterpret_cast<fx4*>(out);

    // ---- 6 batches of 256 slots (1500 = 5n x 3w x 100tt) ----
    for (int m = 0; m < 6; ++m) {
        int s = m * 256 + (int)threadIdx.x;
        if (s < 1500) {
            int n  = s / 300;
            int q  = s - n * 300;
            int w  = q / 100;
            int tl = q - w * 100;
            int tt = ch * CH_ + tl;
            int li = tl + ofs;

            bool boundary;
            if (w == 0)      boundary = (tt == 0) || (tt == 599);
            else if (w == 1) boundary = (tt == 0) || (tt == 299) || (tt == 300) || (tt == 599);
            else             boundary = (tt == 0) || (tt == 199) || (tt == 200) ||
                                        (tt == 399) || (tt == 400) || (tt == 599);

            const float* rc = &raw[li * 75 + n * 15];

            float s0=0.f,s1=0.f,s2=0.f, m0=0.f,m1=0.f,m2=0.f;
            float A00=0.f,A01=0.f,A02=0.f,A11=0.f,A12=0.f,A22=0.f;
            #pragma unroll
            for (int p = 0; p < 5; ++p) {
                float a = rc[p*3+0], c = rc[p*3+1], d = rc[p*3+2];
                s0 += a; s1 += c; s2 += d;
                m0 += w5[p]*a; m1 += w5[p]*c; m2 += w5[p]*d;
                A00 += a*a; A01 += a*c; A02 += a*d;
                A11 += c*c; A12 += c*d; A22 += d*d;
            }
            float mu0 = m0*(1.f/15.f), mu1 = m1*(1.f/15.f), mu2 = m2*(1.f/15.f);

            float inv = 0.2f;
            if (!boundary) {
                #pragma unroll
                for (int dstep = 0; dstep < 2; ++dstep) {
                    const float* rn = rc + (dstep ? 75 : -75);
                    #pragma unroll
                    for (int p = 0; p < 5; ++p) {
                        float a = rn[p*3+0], c = rn[p*3+1], d = rn[p*3+2];
                        s0 += a; s1 += c; s2 += d;
                        A00 += a*a; A01 += a*c; A02 += a*d;
                        A11 += c*c; A12 += c*d; A22 += d*d;
                    }
                }
                inv = 1.f/15.f;
            }

            float mb0 = s0*inv, mb1 = s1*inv, mb2 = s2*inv;
            float e00 = A00*inv - 2.f*mu0*mb0 + 2.f*mu0*mu0;
            float e01 = A01*inv - mu0*mb1 - mb0*mu1 + 2.f*mu0*mu1;
            float e02 = A02*inv - mu0*mb2 - mb0*mu2 + 2.f*mu0*mu2;
            float e11 = A11*inv - 2.f*mu1*mb1 + 2.f*mu1*mu1;
            float e12 = A12*inv - mu1*mb2 - mb1*mu2 + 2.f*mu1*mu2;
            float e22 = A22*inv - 2.f*mu2*mb2 + 2.f*mu2*mu2;

            int base = (int)threadIdx.x * 5;
            obuf[base + 0] = make_float4(e00, e01, e02, mu0);
            obuf[base + 1] = make_float4(e01, e11, e12, mu1);
            obuf[base + 2] = make_float4(e02, e12, e22, mu2);
            obuf[base + 3] = make_float4(mu0, mu1, mu2, 1.f);
        }
        BAR_LDS();

        // ---- cooperative lane-contiguous NONTEMPORAL store of this batch ----
        int nslots  = (1500 - m * 256 < 256) ? (1500 - m * 256) : 256;
        int npieces = nslots * 4;
        #pragma unroll
        for (int k = 0; k < 4; ++k) {
            int f = k * 256 + (int)threadIdx.x;
            if (f < npieces) {
                int sl = f >> 2, pc = f & 3;
                int s2 = m * 256 + sl;
                int n  = s2 / 300;
                int q  = s2 - n * 300;
                int w  = q / 100;
                int tl = q - w * 100;
                int tt = ch * CH_ + tl;
                size_t o = ((size_t)(b * 5 + n) * 1800 + w * 600 + tt) * 4 + pc;
                float4 v = obuf[sl * 5 + pc];
                fx4 nv; nv.x = v.x; nv.y = v.y; nv.z = v.z; nv.w = v.w;
                __builtin_nontemporal_store(nv, &outf4[o]);
            }
        }
        BAR_LDS();
    }
}

extern "C" void kernel_launch(void* const* d_in, const int* in_sizes, int n_in,
                              void* d_out, int out_size, void* d_ws, size_t ws_size,
                              hipStream_t stream) {
    const float* x = (const float*)d_in[0];
    float* out = (float*)d_out;
    gauss_agg_kernel<<<256 * NCH_, 256, 0, stream>>>(x, out);
}